// Round 11
// baseline (254.299 us; speedup 1.0000x reference)
//
#include <hip/hip_runtime.h>
#include <hip/hip_bf16.h>

#define TT    512
#define ISZ   9
#define HH    50
#define NB    16      // batches per block
#define NWAVE 16      // waves 0-7: gang A (tiles 0-7); 8-12: gang B (tiles 8-12); 13-15: x stager
#define NTH   (NWAVE * 64)   // 1024 threads
#define KDIM  64
// K layout (f16, per batch-column), col stride 128 B, buffers toggle +0x800:
//   k=j     : h_j (j=0..49)   [klow = k 0..31 -> gang A cells; khigh = k 32..49 -> gang B]
//   k=50+i  : x_i (i=0..8)
//   k=59..63: zero pad (dead cells j=50,51 dump to k=59,60)
// Bias rides in the MFMA C-input (exact f32, pre-scaled).
// Two-phase skewed pipeline: B runs half a step behind A; each barrier gates
// only the buffer half its consumers need.

typedef _Float16 f16x8_t __attribute__((ext_vector_type(8)));
typedef float    f32x4_t __attribute__((ext_vector_type(4)));

#define L2E    1.44269504088896340736f
#define TWOL2E 2.88539008177792681472f

// barrier draining ONLY lgkmcnt (ds ops) — vmcnt (x prefetch) stays in flight
#define BAR() asm volatile("s_waitcnt lgkmcnt(0)\n\ts_barrier" ::: "memory")

__device__ __forceinline__ unsigned short f16h(float v) {
  _Float16 b = (_Float16)v;
  return __builtin_bit_cast(unsigned short, b);
}
__device__ __forceinline__ float sg_exp2(float z) { return __builtin_amdgcn_exp2f(z); }
__device__ __forceinline__ float rcp_f(float z)   { return __builtin_amdgcn_rcpf(z); }

// LSTM cell: acc = (-zi, -zf, 2zg, -zo) * L2E (+scaled bias). csc = 2*L2E*c.
__device__ __forceinline__ float cell_update(const f32x4_t acc, float& csc) {
  const float pi = sg_exp2(acc[0]);
  const float pf = sg_exp2(acc[1]);
  const float eg = sg_exp2(acc[2]);
  const float po = sg_exp2(acc[3]);
  const float A1 = 1.0f + pi, A2 = 1.0f + eg, A3 = 1.0f + pf;
  const float P  = A1 * A2;
  const float R  = rcp_f(P * A3);
  const float u  = (eg - 1.0f) * TWOL2E;
  const float fv = P * R;               // 1/(1+pf)
  const float ig2 = u * (A3 * R);       // 2L2E * i*g
  csc = fmaf(fv, csc, ig2);
  const float ec = sg_exp2(csc);
  const float r2 = rcp_f((1.0f + po) * (1.0f + ec));
  return (ec - 1.0f) * r2;              // h = o * tanh(c)
}

__global__ __launch_bounds__(NTH, 1) void lstm_mfma(
    const float* __restrict__ x,
    const float* __restrict__ w_ih,
    const float* __restrict__ w_hh,
    const float* __restrict__ b_ih,
    const float* __restrict__ b_hh,
    const float* __restrict__ fc_w,
    const float* __restrict__ fc_b,
    float* __restrict__ out) {
  __shared__ __align__(16) unsigned short hbuf[2][NB * KDIM];  // 2 x 2048 B
  __shared__ float redbuf[NWAVE][NB];

  const int tid = threadIdx.x;
  const int w   = tid >> 6;
  const int l   = tid & 63;
  const int lb  = l & 15;            // batch column
  const int kq  = l >> 4;            // k-quarter 0..3
  const int b0  = blockIdx.x * NB;
  const bool cw = (w < 13);          // compute wave (A: w<8, B: 8<=w<13)

  // ---- zero both h buffers
  for (int i = tid; i < (2 * NB * KDIM) / 2; i += NTH)
    reinterpret_cast<unsigned*>(hbuf)[i] = 0u;

  // x-stager mapping (waves 13-15: 192 lanes, 144 active)
  const int xt = tid - 13 * 64;
  const bool xact = (xt >= 0 && xt < NB * ISZ);
  const int xb = xact ? (xt / ISZ) : 0;
  const int xi = xact ? (xt - xb * ISZ) : 0;
  __syncthreads();
  // ---- x(t=0) into buf0
  if (xact) {
    float xv = x[(size_t)(b0 + xb) * (TT * ISZ) + xi];
    *(unsigned short*)((char*)hbuf[0] + (((xb << 7) + ((50 + xi) << 1)) ^ ((xb & 7) << 4))) = f16h(xv);
  }

  // ---- static A fragment (tile w), f16, weights pre-scaled:
  //   i,f,o rows: * -log2e ; g row: * 2log2e.  rp = 4j+g.
  f16x8_t afrag[2];
  {
    const int rp   = w * 16 + lb;
    const int jA   = rp >> 2;
    const int gA   = rp & 3;
    const int rowA = gA * HH + jA;
    const bool liveA = cw && (jA < HH);
    const float scA = (gA == 2) ? TWOL2E : (-L2E);
#pragma unroll
    for (int ks = 0; ks < 2; ++ks) {
#pragma unroll
      for (int e = 0; e < 8; ++e) {
        const int K = ks * 32 + kq * 8 + e;
        float v = 0.0f;
        if (liveA) {
          if (K < HH)            v = w_hh[rowA * HH + K] * scA;
          else if (K < HH + ISZ) v = w_ih[rowA * ISZ + (K - HH)] * scA;
        }
        afrag[ks][e] = (_Float16)v;
      }
    }
  }

  // ---- per-lane bias C-init (exact f32, pre-scaled) for cell (j0, lb)
  const int j0 = w * 4 + kq;
  const bool live0 = cw && (j0 < HH);
  f32x4_t bias0 = {0.f, 0.f, 0.f, 0.f};
  if (live0) {
#pragma unroll
    for (int r = 0; r < 4; ++r) {
      const float sc = (r == 2) ? TWOL2E : (-L2E);
      bias0[r] = (b_ih[r * HH + j0] + b_hh[r * HH + j0]) * sc;
    }
  }

  // ---- loop-invariant LDS byte addresses (buf0-relative; buf1 = +0x800 imm)
  char* const base = (char*)hbuf[0];
  const int swzb = (lb & 7) << 4;
  const int rd0 = ((lb << 7) + 0  + (kq << 4)) ^ swzb;   // klow  (k 0..31)
  const int rd1 = ((lb << 7) + 64 + (kq << 4)) ^ swzb;   // khigh (k 32..63)
  const int j0c = (j0 < HH) ? j0 : (j0 + 9);             // dead j 50,51 -> k 59,60
  const int wo0 = (((lb << 7) + (j0c << 1)) ^ swzb);
  const int xwo = (((xb << 7) + ((50 + xi) << 1)) ^ ((xb & 7) << 4));

  const float* xp = x + (size_t)(b0 + xb) * (TT * ISZ) + xi;
  float csc = 0.0f, h0 = 0.0f;
  f32x4_t accP;                          // MFMA1 partial (P1 -> P2, both gangs)
  f32x4_t accB = {0.f, 0.f, 0.f, 0.f};   // gang B: full acc carried P2 -> next P1
  float xv_n = 0.0f;                     // stager: x(t+1)
  if (xact) xv_n = xp[ISZ];
  xp += 2 * ISZ;

  // Per iteration T:
  //  β1 : cur.klow complete (h_A(T-1))
  //  P1 : A: read klow, MFMA1.  B: finish step T-1 (trans, write h_B -> cur.khigh),
  //       read klow, MFMA1.     stager: write x(T+1) -> nxt.
  //  β2 : cur.khigh complete (h_B(T-1) + x(T))
  //  P2 : A: read khigh, MFMA2, trans, write h_A(T) -> nxt.klow.
  //       B: read khigh, MFMA2 (save acc).  stager: prefetch x(T+2).
#define ITER(T, CUR, NXT)                                                        \
  BAR();                                                                         \
  if (cw) {                                                                      \
    f16x8_t bb0 = *(const f16x8_t*)(base + rd0 + (CUR));                         \
    if (w >= 8) {                                                                \
      if ((T) > 0) {                                                             \
        h0 = cell_update(accB, csc);                                             \
        *(unsigned short*)(base + wo0 + (CUR)) = f16h(h0);                       \
      }                                                                          \
    }                                                                            \
    accP = __builtin_amdgcn_mfma_f32_16x16x32_f16(afrag[0], bb0, bias0, 0,0,0);  \
  } else {                                                                       \
    if (xact && (T) + 1 < TT) *(unsigned short*)(base + xwo + (NXT)) = f16h(xv_n); \
  }                                                                              \
  BAR();                                                                         \
  if (cw) {                                                                      \
    f16x8_t bb1 = *(const f16x8_t*)(base + rd1 + (CUR));                         \
    f32x4_t a2 = __builtin_amdgcn_mfma_f32_16x16x32_f16(afrag[1], bb1, accP, 0,0,0); \
    if (w < 8) {                                                                 \
      h0 = cell_update(a2, csc);                                                 \
      *(unsigned short*)(base + wo0 + (NXT)) = f16h(h0);                         \
    } else {                                                                     \
      accB = a2;                                                                 \
    }                                                                            \
  } else {                                                                       \
    float xv_new = 0.0f;                                                         \
    if (xact && (T) + 2 < TT) xv_new = *xp;                                      \
    xp += ISZ;                                                                   \
    xv_n = xv_new;                                                               \
  }

  for (int t2 = 0; t2 < TT; t2 += 2) {
    ITER(t2,     0x000, 0x800);   // cur = buf0, nxt = buf1
    ITER(t2 + 1, 0x800, 0x000);   // cur = buf1, nxt = buf0
  }
#undef ITER

  // ---- epilogue peel: gang B finishes step 511 (register-local)
  if (w >= 8 && w < 13) h0 = cell_update(accB, csc);

  // ---- FC epilogue: out[b] = sum_j h_last[j,b]*fc_w[j] + fc_b
  float p = live0 ? h0 * fc_w[j0] : 0.0f;
  p += __shfl_xor(p, 16);
  p += __shfl_xor(p, 32);
  if (l < NB) redbuf[w][l] = p;
  __syncthreads();
  if (tid < NB) {
    float a = fc_b[0];
#pragma unroll
    for (int ww = 0; ww < NWAVE; ++ww) a += redbuf[ww][tid];
    out[b0 + tid] = a;
  }
}

extern "C" void kernel_launch(void* const* d_in, const int* in_sizes, int n_in,
                              void* d_out, int out_size, void* d_ws, size_t ws_size,
                              hipStream_t stream) {
  const float* x    = (const float*)d_in[0];
  const float* w_ih = (const float*)d_in[1];
  const float* w_hh = (const float*)d_in[2];
  const float* b_ih = (const float*)d_in[3];
  const float* b_hh = (const float*)d_in[4];
  const float* fc_w = (const float*)d_in[5];
  const float* fc_b = (const float*)d_in[6];
  float* out = (float*)d_out;
  const int Btot = in_sizes[0] / (TT * ISZ);   // 4096
  dim3 grid(Btot / NB), block(NTH);
  hipLaunchKernelGGL(lstm_mfma, grid, block, 0, stream,
                     x, w_ih, w_hh, b_ih, b_hh, fc_w, fc_b, out);
}

// Round 12
// 212.808 us; speedup vs baseline: 1.1950x; 1.1950x over previous
//
#include <hip/hip_runtime.h>
#include <hip/hip_bf16.h>

#define TT    512
#define ISZ   9
#define HH    50
#define NB    16      // batches per block
#define NWAVE 16      // waves 0-7: gang A (klow h); 8-12: gang B (khigh h); 13-15: x stager
#define NTH   (NWAVE * 64)   // 1024 threads
#define KDIM  64
// K layout (f16, per batch-column), col stride 128 B, buffers toggle +0x800:
//   k=j     : h_j (j=0..49)   [k 0..31 -> gang A; k 32..49 -> gang B]
//   k=50+i  : x_i (i=0..8)    [khigh region, written by stager waves]
//   k=59..63: zero pad (dead cells j=50,51 dump to k=59,60)
// Bias rides in the MFMA C-input (exact f32, pre-scaled).
// Sync: NO s_barrier in the main loop. flags[w] = (last completed step)+1.
// Per step t: poll flags[0..7] >= t -> read klow -> MFMA1 -> poll flags[8..15] >= t
// -> read khigh -> MFMA2 -> trans -> write h(t) -> lgkmcnt(0) -> flags[w] = t+1.

typedef _Float16 f16x8_t __attribute__((ext_vector_type(8)));
typedef float    f32x4_t __attribute__((ext_vector_type(4)));

#define L2E    1.44269504088896340736f
#define TWOL2E 2.88539008177792681472f

__device__ __forceinline__ unsigned short f16h(float v) {
  _Float16 b = (_Float16)v;
  return __builtin_bit_cast(unsigned short, b);
}
__device__ __forceinline__ float sg_exp2(float z) { return __builtin_amdgcn_exp2f(z); }
__device__ __forceinline__ float rcp_f(float z)   { return __builtin_amdgcn_rcpf(z); }

// Poll 8 flag slots (all 64 lanes read f[l&7]; 8 banks, broadcast) until all >= thr.
__device__ __forceinline__ void waitge(volatile const unsigned* f, int l, unsigned thr) {
  unsigned v = f[l & 7];
  if (!__all((int)(v >= thr))) {
    do {
      __builtin_amdgcn_s_sleep(1);
      v = f[l & 7];
    } while (!__all((int)(v >= thr)));
  }
  __asm__ volatile("" ::: "memory");   // fence: no data read hoists above the poll
}

__global__ __launch_bounds__(NTH, 1) void lstm_mfma(
    const float* __restrict__ x,
    const float* __restrict__ w_ih,
    const float* __restrict__ w_hh,
    const float* __restrict__ b_ih,
    const float* __restrict__ b_hh,
    const float* __restrict__ fc_w,
    const float* __restrict__ fc_b,
    float* __restrict__ out) {
  __shared__ __align__(16) unsigned short hbuf[2][NB * KDIM];  // 2 x 2048 B
  __shared__ unsigned flags[NWAVE];
  __shared__ float redbuf[NWAVE][NB];

  const int tid = threadIdx.x;
  const int w   = tid >> 6;          // wave id
  const int l   = tid & 63;
  const int lb  = l & 15;            // batch column
  const int kq  = l >> 4;            // k-quarter 0..3
  const int b0  = blockIdx.x * NB;
  const bool cw = (w < 13);          // compute wave

  // ---- init: zero h buffers, zero flags
  for (int i = tid; i < (2 * NB * KDIM) / 2; i += NTH)
    reinterpret_cast<unsigned*>(hbuf)[i] = 0u;
  if (tid < NWAVE) flags[tid] = 0u;

  // x-stager mapping (waves 13-15: 192 lanes, 144 active)
  const int xt = tid - 13 * 64;
  const bool xact = (xt >= 0 && xt < NB * ISZ);
  const int xb = xact ? (xt / ISZ) : 0;
  const int xi = xact ? (xt - xb * ISZ) : 0;
  __syncthreads();
  // ---- x(t=0) into buf0
  if (xact) {
    float xv = x[(size_t)(b0 + xb) * (TT * ISZ) + xi];
    *(unsigned short*)((char*)hbuf[0] + (((xb << 7) + ((50 + xi) << 1)) ^ ((xb & 7) << 4))) = f16h(xv);
  }
  __syncthreads();   // x(0) + zeros + flags visible before flag-synced loop

  // ---- static A fragment (tile w), f16, weights pre-scaled:
  //   i,f,o rows: * -log2e ; g row: * 2log2e.  rp = 4j+g.
  f16x8_t afrag[2];
  {
    const int rp   = w * 16 + lb;
    const int jA   = rp >> 2;
    const int gA   = rp & 3;
    const int rowA = gA * HH + jA;
    const bool liveA = cw && (jA < HH);
    const float scA = (gA == 2) ? TWOL2E : (-L2E);
#pragma unroll
    for (int ks = 0; ks < 2; ++ks) {
#pragma unroll
      for (int e = 0; e < 8; ++e) {
        const int K = ks * 32 + kq * 8 + e;
        float v = 0.0f;
        if (liveA) {
          if (K < HH)            v = w_hh[rowA * HH + K] * scA;
          else if (K < HH + ISZ) v = w_ih[rowA * ISZ + (K - HH)] * scA;
        }
        afrag[ks][e] = (_Float16)v;
      }
    }
  }

  // ---- per-lane bias C-init (exact f32, pre-scaled) for cell (j0, lb)
  const int j0 = w * 4 + kq;
  const bool live0 = cw && (j0 < HH);
  f32x4_t bias0 = {0.f, 0.f, 0.f, 0.f};
  if (live0) {
#pragma unroll
    for (int r = 0; r < 4; ++r) {
      const float sc = (r == 2) ? TWOL2E : (-L2E);
      bias0[r] = (b_ih[r * HH + j0] + b_hh[r * HH + j0]) * sc;
    }
  }

  // ---- loop-invariant LDS byte addresses (buf0-relative; buf1 = +0x800 imm)
  char* const base = (char*)hbuf[0];
  const int swzb = (lb & 7) << 4;
  const int rd0 = ((lb << 7) + 0  + (kq << 4)) ^ swzb;   // klow  (k 0..31)
  const int rd1 = ((lb << 7) + 64 + (kq << 4)) ^ swzb;   // khigh (k 32..63)
  const int j0c = (j0 < HH) ? j0 : (j0 + 9);             // dead j 50,51 -> k 59,60
  const int wo0 = (((lb << 7) + (j0c << 1)) ^ swzb);
  const int xwo = (((xb << 7) + ((50 + xi) << 1)) ^ ((xb & 7) << 4));

  volatile unsigned* const myflag = flags + w;

  const float* xp = x + (size_t)(b0 + xb) * (TT * ISZ) + xi;
  float csc = 0.0f, h0 = 0.0f;       // csc = c * 2*L2E (pre-scaled cell state)
  float xv_n = 0.0f;                 // x(t+1); prefetch depth 2
  if (xact) xv_n = xp[ISZ];
  xp += 2 * ISZ;

#define STEP(T, CUR, NXT)                                                        \
  {                                                                              \
    const unsigned thr = (unsigned)(T);                                          \
    if (cw) {                                                                    \
      waitge(flags, l, thr);              /* gang A finished step T-1 */         \
      f16x8_t bb0 = *(const f16x8_t*)(base + rd0 + (CUR));                       \
      f32x4_t accP = __builtin_amdgcn_mfma_f32_16x16x32_f16(afrag[0], bb0, bias0, 0,0,0); \
      waitge(flags + 8, l, thr);          /* gang B + x finished step T-1 */     \
      f16x8_t bb1 = *(const f16x8_t*)(base + rd1 + (CUR));                       \
      f32x4_t acc = __builtin_amdgcn_mfma_f32_16x16x32_f16(afrag[1], bb1, accP, 0,0,0); \
      const float pi = sg_exp2(acc[0]);   /* e^-zi  */                           \
      const float pf = sg_exp2(acc[1]);   /* e^-zf  */                           \
      const float eg = sg_exp2(acc[2]);   /* e^+2zg */                           \
      const float po = sg_exp2(acc[3]);   /* e^-zo  */                           \
      const float A1 = 1.0f + pi, A2 = 1.0f + eg, A3 = 1.0f + pf;                \
      const float P  = A1 * A2;                                                  \
      const float R  = rcp_f(P * A3);                                            \
      const float u  = (eg - 1.0f) * TWOL2E;                                     \
      const float fv = P * R;             /* 1/(1+pf) */                         \
      const float ig2 = u * (A3 * R);     /* 2L2E * i*g */                       \
      csc = fmaf(fv, csc, ig2);           /* csc = 2*L2E*c */                    \
      const float ec = sg_exp2(csc);                                             \
      const float r2 = rcp_f((1.0f + po) * (1.0f + ec));                         \
      h0 = (ec - 1.0f) * r2;                                                     \
      *(unsigned short*)(base + wo0 + (NXT)) = f16h(h0);                         \
      __asm__ volatile("s_waitcnt lgkmcnt(0)" ::: "memory");                     \
      if (l == 0) *myflag = thr + 1u;                                            \
    } else {                                                                     \
      float xv_new = 0.0f;                                                       \
      if (xact && (T) + 2 < TT) xv_new = *xp;                                    \
      xp += ISZ;                                                                 \
      waitge(flags, l, thr);              /* WAR: all readers of NXT done */     \
      waitge(flags + 8, l, thr);                                                 \
      if (xact && (T) + 1 < TT) *(unsigned short*)(base + xwo + (NXT)) = f16h(xv_n); \
      __asm__ volatile("s_waitcnt lgkmcnt(0)" ::: "memory");                     \
      if (l == 0) *myflag = thr + 1u;                                            \
      xv_n = xv_new;                                                             \
    }                                                                            \
  }

  for (int t2 = 0; t2 < TT; t2 += 2) {
    STEP(t2,     0x000, 0x800);   // read buf0, write buf1
    STEP(t2 + 1, 0x800, 0x000);   // read buf1, write buf0
  }
#undef STEP

  // ---- FC epilogue: out[b] = sum_j h_last[j,b]*fc_w[j] + fc_b
  float p = live0 ? h0 * fc_w[j0] : 0.0f;
  p += __shfl_xor(p, 16);
  p += __shfl_xor(p, 32);
  if (l < NB) redbuf[w][l] = p;
  __syncthreads();
  if (tid < NB) {
    float a = fc_b[0];
#pragma unroll
    for (int ww = 0; ww < NWAVE; ++ww) a += redbuf[ww][tid];
    out[b0 + tid] = a;
  }
}

extern "C" void kernel_launch(void* const* d_in, const int* in_sizes, int n_in,
                              void* d_out, int out_size, void* d_ws, size_t ws_size,
                              hipStream_t stream) {
  const float* x    = (const float*)d_in[0];
  const float* w_ih = (const float*)d_in[1];
  const float* w_hh = (const float*)d_in[2];
  const float* b_ih = (const float*)d_in[3];
  const float* b_hh = (const float*)d_in[4];
  const float* fc_w = (const float*)d_in[5];
  const float* fc_b = (const float*)d_in[6];
  float* out = (float*)d_out;
  const int Btot = in_sizes[0] / (TT * ISZ);   // 4096
  dim3 grid(Btot / NB), block(NTH);
  hipLaunchKernelGGL(lstm_mfma, grid, block, 0, stream,
                     x, w_ih, w_hh, b_ih, b_hh, fc_w, fc_b, out);
}

// Round 13
// 189.861 us; speedup vs baseline: 1.3394x; 1.1209x over previous
//
#include <hip/hip_runtime.h>
#include <hip/hip_bf16.h>

#define TT    512
#define ISZ   9
#define HH    50
#define NB    16      // batches per block
#define NWAVE 10      // w0-5: tiles (2w,2w+1); w6: tile 12; w7-9: x stagers
#define NTH   (NWAVE * 64)   // 640 threads
#define KDIM  64
// K layout (f16, per batch-column), col stride 128 B, buffers toggle +0x800:
//   k=j     : h_j (j=0..49)
//   k=50+i  : x_i (i=0..8)
//   k=59..63: zero pad (dead cells j=50,51 dump to k=59,60)
// Bias rides in the MFMA C-input (exact f32, pre-scaled).
// 2 tiles per compute wave: one B read feeds 4 MFMAs -> DS reads/CU halve.

typedef _Float16 f16x8_t __attribute__((ext_vector_type(8)));
typedef float    f32x4_t __attribute__((ext_vector_type(4)));

#define L2E    1.44269504088896340736f
#define TWOL2E 2.88539008177792681472f

// barrier draining ONLY lgkmcnt (ds ops) — vmcnt (x prefetch) stays in flight
#define BAR() asm volatile("s_waitcnt lgkmcnt(0)\n\ts_barrier" ::: "memory")

__device__ __forceinline__ unsigned short f16h(float v) {
  _Float16 b = (_Float16)v;
  return __builtin_bit_cast(unsigned short, b);
}
__device__ __forceinline__ float sg_exp2(float z) { return __builtin_amdgcn_exp2f(z); }
__device__ __forceinline__ float rcp_f(float z)   { return __builtin_amdgcn_rcpf(z); }

__global__ __launch_bounds__(NTH, 1) void lstm_mfma(
    const float* __restrict__ x,
    const float* __restrict__ w_ih,
    const float* __restrict__ w_hh,
    const float* __restrict__ b_ih,
    const float* __restrict__ b_hh,
    const float* __restrict__ fc_w,
    const float* __restrict__ fc_b,
    float* __restrict__ out) {
  __shared__ __align__(16) unsigned short hbuf[2][NB * KDIM];  // 2 x 2048 B
  __shared__ float redbuf[NWAVE][NB];

  const int tid = threadIdx.x;
  const int w   = tid >> 6;          // wave id
  const int l   = tid & 63;
  const int lb  = l & 15;            // batch column
  const int kq  = l >> 4;            // k-quarter 0..3
  const int b0  = blockIdx.x * NB;
  const bool cw = (w < 7);           // compute wave
  const bool two = (w < 6);          // 2-tile wave

  // ---- zero both h buffers
  for (int i = tid; i < (2 * NB * KDIM) / 2; i += NTH)
    reinterpret_cast<unsigned*>(hbuf)[i] = 0u;

  // x-stager mapping (waves 7-9: 192 lanes, 144 active)
  const int xt = tid - 7 * 64;
  const bool xact = (xt >= 0 && xt < NB * ISZ);
  const int xb = xact ? (xt / ISZ) : 0;
  const int xi = xact ? (xt - xb * ISZ) : 0;
  __syncthreads();
  // ---- x(t=0) into buf0
  if (xact) {
    float xv = x[(size_t)(b0 + xb) * (TT * ISZ) + xi];
    *(unsigned short*)((char*)hbuf[0] + (((xb << 7) + ((50 + xi) << 1)) ^ ((xb & 7) << 4))) = f16h(xv);
  }

  // ---- static A fragments (tiles tA, tB), f16, weights pre-scaled:
  //   i,f,o rows: * -log2e ; g row: * 2log2e.  rp = 4j+g.
  const int tA = two ? (2 * w)     : 12;   // w6 -> tile 12; stagers dead
  const int tB = two ? (2 * w + 1) : 12;
  f16x8_t afrag[2][2];
#pragma unroll
  for (int tt = 0; tt < 2; ++tt) {
    const int tile = tt ? tB : tA;
    const bool actT = cw && (two || tt == 0);
    const int rp   = tile * 16 + lb;
    const int jA   = rp >> 2;
    const int gA   = rp & 3;
    const int rowA = gA * HH + jA;
    const bool liveA = actT && (jA < HH);
    const float scA = (gA == 2) ? TWOL2E : (-L2E);
#pragma unroll
    for (int ks = 0; ks < 2; ++ks) {
#pragma unroll
      for (int e = 0; e < 8; ++e) {
        const int K = ks * 32 + kq * 8 + e;
        float v = 0.0f;
        if (liveA) {
          if (K < HH)            v = w_hh[rowA * HH + K] * scA;
          else if (K < HH + ISZ) v = w_ih[rowA * ISZ + (K - HH)] * scA;
        }
        afrag[tt][ks][e] = (_Float16)v;
      }
    }
  }

  // ---- per-lane bias C-init (exact f32, pre-scaled) for cells (j0, lb), (j1, lb)
  const int j0 = tA * 4 + kq;        // w6: 48..51 (50,51 dead)
  const int j1 = tB * 4 + kq;        // w<6: always <48 (live)
  const bool live0 = cw && (j0 < HH);
  f32x4_t bias0 = {0.f, 0.f, 0.f, 0.f};
  f32x4_t bias1 = {0.f, 0.f, 0.f, 0.f};
#pragma unroll
  for (int r = 0; r < 4; ++r) {
    const float sc = (r == 2) ? TWOL2E : (-L2E);
    if (live0) bias0[r] = (b_ih[r * HH + j0] + b_hh[r * HH + j0]) * sc;
    if (two)   bias1[r] = (b_ih[r * HH + j1] + b_hh[r * HH + j1]) * sc;
  }

  // ---- loop-invariant LDS byte addresses (buf0-relative; buf1 = +0x800 imm)
  char* const base = (char*)hbuf[0];
  const int swzb = (lb & 7) << 4;
  const int rd0 = ((lb << 7) + 0  + (kq << 4)) ^ swzb;   // klow  (k 0..31)
  const int rd1 = ((lb << 7) + 64 + (kq << 4)) ^ swzb;   // khigh (k 32..63)
  const int j0c = (j0 < HH) ? j0 : (j0 + 9);             // dead j 50,51 -> k 59,60
  const int woA = (((lb << 7) + (j0c << 1)) ^ swzb);
  const int woB = (((lb << 7) + (j1  << 1)) ^ swzb);
  const int xwo = (((xb << 7) + ((50 + xi) << 1)) ^ ((xb & 7) << 4));

  const float* xp = x + (size_t)(b0 + xb) * (TT * ISZ) + xi;
  float csc0 = 0.0f, h0 = 0.0f, csc1 = 0.0f, h1 = 0.0f;
  float xv_n = 0.0f;                 // x(t+1); prefetch depth 2
  if (xact) xv_n = xp[ISZ];
  xp += 2 * ISZ;

  // cell update: acc = (-zi,-zf,2zg,-zo)*L2E + scaled bias. cscv = 2*L2E*c.
  // csc' = (P*csc + (eg-1)*2L2E*A3) * R  — rcp latency overlaps P*csc.
#define CELL(acc, cscv, hv, wo, WOFF)                                            \
  {                                                                              \
    const float pi = sg_exp2(acc[0]);                                            \
    const float pf = sg_exp2(acc[1]);                                            \
    const float eg = sg_exp2(acc[2]);                                            \
    const float po = sg_exp2(acc[3]);                                            \
    const float A1 = 1.0f + pi, A2 = 1.0f + eg, A3 = 1.0f + pf;                  \
    const float P  = A1 * A2;                                                    \
    const float R  = rcp_f(P * A3);                                              \
    const float t1 = fmaf(P, cscv, (eg - 1.0f) * TWOL2E * A3);                   \
    cscv = t1 * R;                                                               \
    const float ec = sg_exp2(cscv);                                              \
    const float r2 = rcp_f((1.0f + po) * (1.0f + ec));                           \
    hv = (ec - 1.0f) * r2;                                                       \
    *(unsigned short*)(base + (wo) + (WOFF)) = f16h(hv);                         \
  }

#define STEP(T, CUR, NXT)                                                        \
  if (cw) {                                                                      \
    BAR();                                                                       \
    f16x8_t bb0 = *(const f16x8_t*)(base + rd0 + (CUR));                         \
    f16x8_t bb1 = *(const f16x8_t*)(base + rd1 + (CUR));                         \
    f32x4_t accA = __builtin_amdgcn_mfma_f32_16x16x32_f16(afrag[0][0], bb0, bias0, 0,0,0); \
    f32x4_t accB;                                                                \
    if (two) accB = __builtin_amdgcn_mfma_f32_16x16x32_f16(afrag[1][0], bb0, bias1, 0,0,0); \
    accA = __builtin_amdgcn_mfma_f32_16x16x32_f16(afrag[0][1], bb1, accA, 0,0,0); \
    if (two) accB = __builtin_amdgcn_mfma_f32_16x16x32_f16(afrag[1][1], bb1, accB, 0,0,0); \
    CELL(accA, csc0, h0, woA, NXT);                                              \
    if (two) CELL(accB, csc1, h1, woB, NXT);                                     \
  } else {                                                                       \
    float xv_new = 0.0f;                                                         \
    if (xact && (T) + 2 < TT) xv_new = *xp;                                      \
    xp += ISZ;                                                                   \
    BAR();                                                                       \
    if (xact && (T) + 1 < TT) *(unsigned short*)(base + xwo + (NXT)) = f16h(xv_n); \
    xv_n = xv_new;                                                               \
  }

  for (int t2 = 0; t2 < TT; t2 += 2) {
    STEP(t2,     0x000, 0x800);   // read buf0, write buf1
    STEP(t2 + 1, 0x800, 0x000);   // read buf1, write buf0
  }
#undef STEP
#undef CELL

  // ---- FC epilogue: out[b] = sum_j h_last[j,b]*fc_w[j] + fc_b
  float p = live0 ? h0 * fc_w[j0] : 0.0f;
  if (two) p += h1 * fc_w[j1];
  p += __shfl_xor(p, 16);
  p += __shfl_xor(p, 32);
  if (l < NB) redbuf[w][l] = p;
  __syncthreads();
  if (tid < NB) {
    float a = fc_b[0];
#pragma unroll
    for (int ww = 0; ww < NWAVE; ++ww) a += redbuf[ww][tid];
    out[b0 + tid] = a;
  }
}

extern "C" void kernel_launch(void* const* d_in, const int* in_sizes, int n_in,
                              void* d_out, int out_size, void* d_ws, size_t ws_size,
                              hipStream_t stream) {
  const float* x    = (const float*)d_in[0];
  const float* w_ih = (const float*)d_in[1];
  const float* w_hh = (const float*)d_in[2];
  const float* b_ih = (const float*)d_in[3];
  const float* b_hh = (const float*)d_in[4];
  const float* fc_w = (const float*)d_in[5];
  const float* fc_b = (const float*)d_in[6];
  float* out = (float*)d_out;
  const int Btot = in_sizes[0] / (TT * ISZ);   // 4096
  dim3 grid(Btot / NB), block(NTH);
  hipLaunchKernelGGL(lstm_mfma, grid, block, 0, stream,
                     x, w_ih, w_hh, b_ih, b_hh, fc_w, fc_b, out);
}